// Round 1
// 2261.629 us; speedup vs baseline: 1.2619x; 1.2619x over previous
//
#include <hip/hip_runtime.h>

// Problem constants
#define S_LEN 128
#define B_SZ  128
#define H_SZ  512
#define V_SZ  10000
#define VP_SZ 10240   // V padded to 128-multiple for GEMM tiles

typedef _Float16 half8 __attribute__((ext_vector_type(8)));
typedef float floatx4 __attribute__((ext_vector_type(4)));
typedef unsigned long long u64;

__device__ __forceinline__ floatx4 mfma16(half8 a, half8 b, floatx4 c) {
    return __builtin_amdgcn_mfma_f32_16x16x32_f16(a, b, c, 0, 0, 0);
}

// Fast tanh: clamp keeps exp in range; |err| ~1e-6 << fp16 noise.
__device__ __forceinline__ float fast_tanh(float x) {
    x = fminf(15.f, fmaxf(-15.f, x));
    float e = __expf(2.f * x);
    return (e - 1.f) / (e + 1.f);
}

// Device-coherent (cross-XCD) 16B h-fragment load: two 8B agent-scope RELAXED
// atomic loads -> global_load_dwordx2 with device-scope bits. They bypass the
// non-coherent per-XCD L2 (served at MALL/IC), so NO acquire fence / buffer_inv
// is ever needed on the consumer side.
__device__ __forceinline__ half8 load_h8_dev(const _Float16* p) {
    const u64* q = (const u64*)p;
    u64 lo = __hip_atomic_load(q,     __ATOMIC_RELAXED, __HIP_MEMORY_SCOPE_AGENT);
    u64 hi = __hip_atomic_load(q + 1, __ATOMIC_RELAXED, __HIP_MEMORY_SCOPE_AGENT);
    union { u64 u[2]; half8 v; } w;
    w.u[0] = lo; w.u[1] = hi;
    return w.v;
}

__device__ __forceinline__ void spin_ge(const unsigned* p, unsigned v) {
    while (__hip_atomic_load(p, __ATOMIC_RELAXED, __HIP_MEMORY_SCOPE_AGENT) < v)
        __builtin_amdgcn_s_sleep(1);
}

// ---------------- small prep kernels ----------------
__global__ void cast_f16_kernel(const float* __restrict__ src,
                                _Float16* __restrict__ dst, int n) {
    int i = blockIdx.x * 256 + threadIdx.x;
    if (i < n) dst[i] = (_Float16)src[i];
}

__global__ void build_wout_kernel(const float* __restrict__ W,
                                  _Float16* __restrict__ dst,
                                  unsigned* __restrict__ cnt) {
    int i = blockIdx.x * 256 + threadIdx.x;
    if (i < VP_SZ * H_SZ) {
        int row = i >> 9;
        int k = i & 511;
        dst[i] = (row < V_SZ) ? (_Float16)W[(size_t)row * H_SZ + k] : (_Float16)0.f;
    }
    if (i < 4096) cnt[i] = 0;   // zero flag slots (ws is poisoned each call)
}

// ---------------- generic fp16 GEMM: C[m,n] = sum_k A[m,k]*Bt[n,k] + bias[n] ----------------
// 128x128 tile, BK=64, padded LDS (2-way-free bank pattern), 2x2 waves, 4x4 MFMA tiles/wave.
#define TK 64
#define LDSS 72   // 64 + 8 halves pad -> ds_read_b128 2-way conflict only (free)

__global__ __launch_bounds__(256) void gemm_f16_kernel(
    const _Float16* __restrict__ A, int lda, int M,
    const _Float16* __restrict__ Bt, int ldb,
    float* __restrict__ C, long ldc, int Nstore,
    const float* __restrict__ bias, int K)
{
    __shared__ __align__(16) _Float16 sA[128 * LDSS];
    __shared__ __align__(16) _Float16 sB[128 * LDSS];
    const int m0 = blockIdx.x * 128;
    const int n0 = blockIdx.y * 128;
    const int tid = threadIdx.x;
    const int lane = tid & 63;
    const int wave = tid >> 6;
    const int wr = wave >> 1, wc = wave & 1;
    const int quad = lane >> 4, l16 = lane & 15;

    floatx4 acc[4][4];
#pragma unroll
    for (int i = 0; i < 4; ++i)
#pragma unroll
        for (int j = 0; j < 4; ++j) acc[i][j] = (floatx4){0.f, 0.f, 0.f, 0.f};

    for (int k0 = 0; k0 < K; k0 += TK) {
#pragma unroll
        for (int r = 0; r < 4; ++r) {
            int idx = r * 256 + tid;           // 0..1023 -> 128 rows x 8 chunks
            int row = idx >> 3;
            int kc = (idx & 7) * 8;
            int ga = m0 + row; if (ga >= M) ga = M - 1;   // clamp (stores guarded)
            half8 va = *(const half8*)(A + (size_t)ga * lda + k0 + kc);
            *(half8*)(sA + row * LDSS + kc) = va;
            half8 vb = *(const half8*)(Bt + (size_t)(n0 + row) * ldb + k0 + kc);
            *(half8*)(sB + row * LDSS + kc) = vb;
        }
        __syncthreads();
#pragma unroll
        for (int ks = 0; ks < TK; ks += 32) {
            half8 af[4], bf[4];
#pragma unroll
            for (int i = 0; i < 4; ++i)
                af[i] = *(const half8*)(sA + (wr * 64 + i * 16 + l16) * LDSS + ks + quad * 8);
#pragma unroll
            for (int j = 0; j < 4; ++j)
                bf[j] = *(const half8*)(sB + (wc * 64 + j * 16 + l16) * LDSS + ks + quad * 8);
#pragma unroll
            for (int i = 0; i < 4; ++i)
#pragma unroll
                for (int j = 0; j < 4; ++j)
                    acc[i][j] = mfma16(af[i], bf[j], acc[i][j]);
        }
        __syncthreads();
    }
    // epilogue: D mapping col=lane&15, row=quad*4+reg (dtype-independent, m89/m101)
#pragma unroll
    for (int j = 0; j < 4; ++j) {
        int colg = n0 + wc * 64 + j * 16 + l16;
        if (colg >= Nstore) continue;
        float bb = bias[colg];
#pragma unroll
        for (int i = 0; i < 4; ++i) {
#pragma unroll
            for (int r = 0; r < 4; ++r) {
                int rowg = m0 + wr * 64 + i * 16 + quad * 4 + r;
                if (rowg < M) C[(size_t)rowg * ldc + colg] = acc[i][j][r] + bb;
            }
        }
    }
}

// ---------------- persistent recurrence kernel ----------------
// Grid: 128 wgs = layer(2) x batch-group(8, 16 rows) x H-slice(8, 64 cols).
// Weight A-frags pinned in VGPRs; MFMA operands SWAPPED vs classic layout
// (a=weights, b=h) so each lane's D regs are 4 CONSECUTIVE output columns of
// one batch row -> single packed 8B device-scope store, no transpose.
// All h exchange + flags use agent-scope RELAXED atomics (sc1, device-coherent
// point): no buffer_inv / buffer_wbl2 anywhere in the loop. Ordering
// data-before-flag comes from the vmcnt(0) drain __syncthreads implies.
// Flags are per-producer write-once slots, padded 128B, polled by 8-16 lanes
// in parallel. Layer 0 never waits on layer 1 -> deadlock-free; 128 wgs
// always co-resident.
__global__ __launch_bounds__(256, 1) void rnn_persistent(
    const int* __restrict__ tok, const float* __restrict__ emb2,
    const _Float16* __restrict__ wih16, const _Float16* __restrict__ whh16,
    const float* __restrict__ b_hh,
    _Float16* __restrict__ hs0, _Float16* __restrict__ hs1,
    float* __restrict__ hfinal, unsigned* __restrict__ flags)
{
    const int wg = blockIdx.x;
    const int layer = wg >> 6;
    const int bg = (wg >> 3) & 7;
    const int hw = wg & 7;
    const int tid = threadIdx.x;
    const int lane = tid & 63;
    const int wave = tid >> 6;
    const int quad = lane >> 4, l16 = lane & 15;
    const int b0 = bg * 16;
    const int wcol = hw * 64 + wave * 16 + l16;       // weight row this lane loads (A-frag)
    const int ocol = hw * 64 + wave * 16 + quad * 4;  // lane's 4 output columns
    const int brow = b0 + l16;                        // lane's batch row

    // Preload weight A-fragments: A[m][k]=W[ocol_m][k] -> lane m=l16 reads W row wcol,
    // k = kk*32 + quad*8 contiguous 16B. (Same bytes as the old B-frag load.)
    half8 bf_hh[16];
    const _Float16* whh = whh16 + (size_t)layer * H_SZ * H_SZ + (size_t)wcol * H_SZ;
#pragma unroll
    for (int kk = 0; kk < 16; ++kk)
        bf_hh[kk] = *(const half8*)(whh + kk * 32 + quad * 8);
    half8 bf_ih[16];
    if (layer == 1) {
        const _Float16* wih = wih16 + (size_t)H_SZ * H_SZ + (size_t)wcol * H_SZ;
#pragma unroll
        for (int kk = 0; kk < 16; ++kk)
            bf_ih[kk] = *(const half8*)(wih + kk * 32 + quad * 8);
    }
    floatx4 bias1 = (floatx4){0.f, 0.f, 0.f, 0.f};
    if (layer == 1) bias1 = *(const floatx4*)(b_hh + H_SZ + ocol);

    unsigned* my_flag = flags + ((layer * 8 + bg) * 8 + hw) * 32;  // 128B-padded slot

    for (int t = 0; t < S_LEN; ++t) {
        // ---- parallel flag spin (device-scope relaxed loads; no cache inv) ----
        if (layer == 0) {
            if (t > 0 && tid < 8)
                spin_ge(flags + (bg * 8 + tid) * 32, (unsigned)t);       // h0[t] ready
        } else {
            if (tid < 8)
                spin_ge(flags + (bg * 8 + tid) * 32, (unsigned)(t + 1)); // h0[t+1] ready
            else if (tid < 16 && t > 0)
                spin_ge(flags + (64 + bg * 8 + (tid - 8)) * 32, (unsigned)t); // h1[t] ready
        }
        __syncthreads();

        floatx4 acc;
        if (layer == 0) {
            const int tk = tok[t * B_SZ + brow];
            floatx4 a0 = *(const floatx4*)(emb2 + (size_t)tk * H_SZ + ocol);  // includes b_hh[0]
            floatx4 a1 = (floatx4){0.f, 0.f, 0.f, 0.f};
            const _Float16* hp = hs0 + ((size_t)t * B_SZ + brow) * H_SZ;
            half8 hb[16];
#pragma unroll
            for (int kk = 0; kk < 16; ++kk)       // issue all 32 8B loads up-front
                hb[kk] = load_h8_dev(hp + kk * 32 + quad * 8);
#pragma unroll
            for (int kk = 0; kk < 8; ++kk) {      // two chains hide MFMA dep latency
                a0 = mfma16(bf_hh[kk], hb[kk], a0);
                a1 = mfma16(bf_hh[kk + 8], hb[kk + 8], a1);
            }
            acc = a0 + a1;
        } else {
            floatx4 a0 = bias1;
            floatx4 a1 = (floatx4){0.f, 0.f, 0.f, 0.f};
            floatx4 a2 = (floatx4){0.f, 0.f, 0.f, 0.f};
            floatx4 a3 = (floatx4){0.f, 0.f, 0.f, 0.f};
            const _Float16* h0t = hs0 + ((size_t)(t + 1) * B_SZ + brow) * H_SZ;
            const _Float16* h1p = hs1 + ((size_t)t * B_SZ + brow) * H_SZ;
            half8 hb[16], hc[16];
#pragma unroll
            for (int kk = 0; kk < 16; ++kk)
                hb[kk] = load_h8_dev(h0t + kk * 32 + quad * 8);
#pragma unroll
            for (int kk = 0; kk < 16; ++kk)
                hc[kk] = load_h8_dev(h1p + kk * 32 + quad * 8);
#pragma unroll
            for (int kk = 0; kk < 8; ++kk) {      // four chains
                a0 = mfma16(bf_ih[kk], hb[kk], a0);
                a1 = mfma16(bf_ih[kk + 8], hb[kk + 8], a1);
                a2 = mfma16(bf_hh[kk], hc[kk], a2);
                a3 = mfma16(bf_hh[kk + 8], hc[kk + 8], a3);
            }
            acc = (a0 + a1) + (a2 + a3);
        }

        // lane holds preact for batch row `brow`, cols ocol..ocol+3 -> pack 4 fp16
        float hv[4];
#pragma unroll
        for (int r = 0; r < 4; ++r) hv[r] = fast_tanh(acc[r]);
        union { _Float16 h[4]; u64 u; } pk;
#pragma unroll
        for (int r = 0; r < 4; ++r) pk.h[r] = (_Float16)hv[r];

        _Float16* hdst = (layer ? hs1 : hs0)
                       + ((size_t)(t + 1) * B_SZ + brow) * H_SZ + ocol;
        __hip_atomic_store((u64*)hdst, pk.u, __ATOMIC_RELAXED, __HIP_MEMORY_SCOPE_AGENT);
        if (t == S_LEN - 1) {
            floatx4 f = (floatx4){hv[0], hv[1], hv[2], hv[3]};
            *(floatx4*)(hfinal + ((size_t)layer * B_SZ + brow) * H_SZ + ocol) = f;
        }

        __syncthreads();   // compiler drains vmcnt(0) before s_barrier -> all lanes'
                           // device-scope stores are visible at the coherence point
        if (tid == 0)
            __hip_atomic_store(my_flag, (unsigned)(t + 1),
                               __ATOMIC_RELAXED, __HIP_MEMORY_SCOPE_AGENT);
    }
}

// ---------------- launch ----------------
extern "C" void kernel_launch(void* const* d_in, const int* in_sizes, int n_in,
                              void* d_out, int out_size, void* d_ws, size_t ws_size,
                              hipStream_t stream) {
    const int*   tok    = (const int*)d_in[0];
    const float* hidden = (const float*)d_in[1];
    const float* emb    = (const float*)d_in[2];
    const float* W_ih   = (const float*)d_in[3];
    const float* W_hh   = (const float*)d_in[4];
    const float* b_hh   = (const float*)d_in[5];
    const float* W_out  = (const float*)d_in[6];
    const float* b_out  = (const float*)d_in[7];
    float* out = (float*)d_out;

    char* ws = (char*)d_ws;
    size_t off = 0;
    auto alloc = [&](size_t bytes) -> void* {
        void* p = ws + off;
        off += (bytes + 255) & ~(size_t)255;
        return p;
    };
    _Float16* emb16  = (_Float16*)alloc((size_t)V_SZ * H_SZ * 2);
    _Float16* wih16  = (_Float16*)alloc((size_t)2 * H_SZ * H_SZ * 2);
    _Float16* whh16  = (_Float16*)alloc((size_t)2 * H_SZ * H_SZ * 2);
    _Float16* wout16 = (_Float16*)alloc((size_t)VP_SZ * H_SZ * 2);
    float*    emb2   = (float*)alloc((size_t)V_SZ * H_SZ * 4);
    _Float16* hs0    = (_Float16*)alloc((size_t)(S_LEN + 1) * B_SZ * H_SZ * 2);
    _Float16* hs1    = (_Float16*)alloc((size_t)(S_LEN + 1) * B_SZ * H_SZ * 2);
    unsigned* cnt    = (unsigned*)alloc(4096 * sizeof(unsigned));   // 128 flag slots x 128B
    // total ws use ~77 MB

    cast_f16_kernel<<<dim3((V_SZ * H_SZ + 255) / 256), dim3(256), 0, stream>>>(emb, emb16, V_SZ * H_SZ);
    cast_f16_kernel<<<dim3((2 * H_SZ * H_SZ + 255) / 256), dim3(256), 0, stream>>>(W_ih, wih16, 2 * H_SZ * H_SZ);
    cast_f16_kernel<<<dim3((2 * H_SZ * H_SZ + 255) / 256), dim3(256), 0, stream>>>(W_hh, whh16, 2 * H_SZ * H_SZ);
    cast_f16_kernel<<<dim3((B_SZ * H_SZ + 255) / 256), dim3(256), 0, stream>>>(hidden, hs0, B_SZ * H_SZ);
    cast_f16_kernel<<<dim3((B_SZ * H_SZ + 255) / 256), dim3(256), 0, stream>>>(hidden + (size_t)B_SZ * H_SZ, hs1, B_SZ * H_SZ);
    build_wout_kernel<<<dim3((VP_SZ * H_SZ + 255) / 256), dim3(256), 0, stream>>>(W_out, wout16, cnt);

    // emb2[v,:] = emb[v,:] @ W_ih[0].T + b_hh[0]  (M=10000, N=512, K=512)
    gemm_f16_kernel<<<dim3(79, 4), dim3(256), 0, stream>>>(
        emb16, H_SZ, V_SZ, wih16, H_SZ, emb2, (long)H_SZ, H_SZ, b_hh, H_SZ);

    // full recurrence (both layers, pipelined), writes hs0/hs1 slots 1..128 and h_final
    rnn_persistent<<<dim3(128), dim3(256), 0, stream>>>(
        tok, emb2, wih16, whh16, b_hh, hs0, hs1,
        out + (size_t)S_LEN * B_SZ * V_SZ, cnt);

    // logits[t*B+b, :] = h1[t,b,:] @ W_out.T + b_out  (M=16384, N=10240->10000, K=512)
    gemm_f16_kernel<<<dim3(128, 80), dim3(256), 0, stream>>>(
        hs1 + (size_t)B_SZ * H_SZ, H_SZ, S_LEN * B_SZ, wout16, H_SZ,
        out, (long)V_SZ, V_SZ, b_out, H_SZ);
}

// Round 2
// 1456.275 us; speedup vs baseline: 1.9598x; 1.5530x over previous
//
#include <hip/hip_runtime.h>

// Problem constants
#define S_LEN 128
#define B_SZ  128
#define H_SZ  512
#define V_SZ  10000
#define VP_SZ 10240   // V padded to 128-multiple for GEMM tiles

typedef _Float16 half8 __attribute__((ext_vector_type(8)));
typedef float floatx4 __attribute__((ext_vector_type(4)));
typedef unsigned int u32;
typedef unsigned long long u64;
typedef u32 u32x4 __attribute__((ext_vector_type(4)));

#define CANARY16 0x7C00u      // fp16 +inf: tanh output can never be this
#define CANARY32 0x7C007C00u

__device__ __forceinline__ floatx4 mfma16(half8 a, half8 b, floatx4 c) {
    return __builtin_amdgcn_mfma_f32_16x16x32_f16(a, b, c, 0, 0, 0);
}

// Fast tanh: clamp keeps exp in range; |err| ~1e-6 << fp16 noise.
__device__ __forceinline__ float fast_tanh(float x) {
    x = fminf(15.f, fmaxf(-15.f, x));
    float e = __expf(2.f * x);
    return (e - 1.f) / (e + 1.f);
}

// 16B device-coherent load: bypasses L1 (sc0) and the non-coherent per-XCD L2
// (sc1) -> served at the IC/coherence point. NOT atomic -- per-element canary
// checks make any sub-16B tearing harmless. Issue several, then one
// vmcnt(0)+sched_barrier(0) (rule 18) before reading the results.
__device__ __forceinline__ u32x4 ld16_sc(const void* p) {
    u32x4 v;
    asm volatile("global_load_dwordx4 %0, %1, off sc0 sc1"
                 : "=&v"(v) : "v"(p));
    return v;
}

__device__ __forceinline__ bool has_canary(u32x4 v) {
    bool b = false;
#pragma unroll
    for (int i = 0; i < 4; ++i) {
        u32 x = v[i];
        b = b || ((x & 0xFFFFu) == CANARY16) || ((x >> 16) == CANARY16);
    }
    return b;
}

// global -> LDS direct (16B). LDS dest must be wave-uniform base + lane*16.
__device__ __forceinline__ void gload_lds16(const _Float16* g, _Float16* l) {
    __builtin_amdgcn_global_load_lds(
        (const __attribute__((address_space(1))) void*)g,
        (__attribute__((address_space(3))) void*)l, 16, 0, 0);
}

// ---------------- small prep kernels ----------------
__global__ void cast_f16_kernel(const float* __restrict__ src,
                                _Float16* __restrict__ dst, int n) {
    int i = blockIdx.x * 256 + threadIdx.x;
    if (i < n) dst[i] = (_Float16)src[i];
}

__global__ void build_wout_kernel(const float* __restrict__ W,
                                  _Float16* __restrict__ dst) {
    int i = blockIdx.x * 256 + threadIdx.x;
    if (i < VP_SZ * H_SZ) {
        int row = i >> 9;
        int k = i & 511;
        dst[i] = (row < V_SZ) ? (_Float16)W[(size_t)row * H_SZ + k] : (_Float16)0.f;
    }
}

// Pre-poison hs0/hs1 slots 1..S with the canary so consumers can poll data
// directly (no flags). Slot 0 holds the real initial hidden state.
__global__ void poison_kernel(_Float16* __restrict__ hs0,
                              _Float16* __restrict__ hs1) {
    const size_t nv = (size_t)S_LEN * B_SZ * H_SZ / 8;   // u32x4 chunks per buffer
    size_t i = (size_t)blockIdx.x * 256 + threadIdx.x;
    u32x4 c = {CANARY32, CANARY32, CANARY32, CANARY32};
    if (i < nv)
        *(u32x4*)(hs0 + (size_t)B_SZ * H_SZ + i * 8) = c;
    else if (i < 2 * nv)
        *(u32x4*)(hs1 + (size_t)B_SZ * H_SZ + (i - nv) * 8) = c;
}

// ---------------- generic fp16 GEMM (used for emb2 only; has M-edge clamp) ----
#define TK 64
#define LDSS 72

__global__ __launch_bounds__(256) void gemm_f16_kernel(
    const _Float16* __restrict__ A, int lda, int M,
    const _Float16* __restrict__ Bt, int ldb,
    float* __restrict__ C, long ldc, int Nstore,
    const float* __restrict__ bias, int K)
{
    __shared__ __align__(16) _Float16 sA[128 * LDSS];
    __shared__ __align__(16) _Float16 sB[128 * LDSS];
    const int m0 = blockIdx.x * 128;
    const int n0 = blockIdx.y * 128;
    const int tid = threadIdx.x;
    const int lane = tid & 63;
    const int wave = tid >> 6;
    const int wr = wave >> 1, wc = wave & 1;
    const int quad = lane >> 4, l16 = lane & 15;

    floatx4 acc[4][4];
#pragma unroll
    for (int i = 0; i < 4; ++i)
#pragma unroll
        for (int j = 0; j < 4; ++j) acc[i][j] = (floatx4){0.f, 0.f, 0.f, 0.f};

    for (int k0 = 0; k0 < K; k0 += TK) {
#pragma unroll
        for (int r = 0; r < 4; ++r) {
            int idx = r * 256 + tid;
            int row = idx >> 3;
            int kc = (idx & 7) * 8;
            int ga = m0 + row; if (ga >= M) ga = M - 1;
            half8 va = *(const half8*)(A + (size_t)ga * lda + k0 + kc);
            *(half8*)(sA + row * LDSS + kc) = va;
            half8 vb = *(const half8*)(Bt + (size_t)(n0 + row) * ldb + k0 + kc);
            *(half8*)(sB + row * LDSS + kc) = vb;
        }
        __syncthreads();
#pragma unroll
        for (int ks = 0; ks < TK; ks += 32) {
            half8 af[4], bf[4];
#pragma unroll
            for (int i = 0; i < 4; ++i)
                af[i] = *(const half8*)(sA + (wr * 64 + i * 16 + l16) * LDSS + ks + quad * 8);
#pragma unroll
            for (int j = 0; j < 4; ++j)
                bf[j] = *(const half8*)(sB + (wc * 64 + j * 16 + l16) * LDSS + ks + quad * 8);
#pragma unroll
            for (int i = 0; i < 4; ++i)
#pragma unroll
                for (int j = 0; j < 4; ++j)
                    acc[i][j] = mfma16(af[i], bf[j], acc[i][j]);
        }
        __syncthreads();
    }
#pragma unroll
    for (int j = 0; j < 4; ++j) {
        int colg = n0 + wc * 64 + j * 16 + l16;
        if (colg >= Nstore) continue;
        float bb = bias[colg];
#pragma unroll
        for (int i = 0; i < 4; ++i) {
#pragma unroll
            for (int r = 0; r < 4; ++r) {
                int rowg = m0 + wr * 64 + i * 16 + quad * 4 + r;
                if (rowg < M) C[(size_t)rowg * ldc + colg] = acc[i][j][r] + bb;
            }
        }
    }
}

// ---------------- m97-style GEMM for logits: global_load_lds + T2 swizzle ----
// M=16384, N=10240, K=512: all dims exact multiples -> no edge guards on M/N
// tile placement. LDS linear [128 rows][64 halves]; source-swizzled
// (sub ^= row&7 on 16B slots) + same XOR on the frag read (rule 21).
__global__ __launch_bounds__(256) void gemm_lds_kernel(
    const _Float16* __restrict__ A,    // [16384][512] f16
    const _Float16* __restrict__ Bt,   // [10240][512] f16
    float* __restrict__ C,             // ldc = V_SZ, Nstore = V_SZ
    const float* __restrict__ bias)
{
    __shared__ __align__(16) _Float16 sA[128 * 64];
    __shared__ __align__(16) _Float16 sB[128 * 64];
    const int m0 = blockIdx.x * 128;
    const int n0 = blockIdx.y * 128;
    const int tid = threadIdx.x;
    const int lane = tid & 63;
    const int wave = tid >> 6;
    const int wr = wave >> 1, wc = wave & 1;
    const int quad = lane >> 4, l16 = lane & 15;

    floatx4 acc[4][4];
#pragma unroll
    for (int i = 0; i < 4; ++i)
#pragma unroll
        for (int j = 0; j < 4; ++j) acc[i][j] = (floatx4){0.f, 0.f, 0.f, 0.f};

    for (int k0 = 0; k0 < H_SZ; k0 += 64) {
#pragma unroll
        for (int r = 0; r < 4; ++r) {
            int c = r * 256 + tid;          // 1024 16B chunks per matrix tile
            int row = c >> 3;
            int sub = c & 7;
            int subs = sub ^ (row & 7);     // inverse swizzle on SOURCE
            gload_lds16(A + (size_t)(m0 + row) * H_SZ + k0 + subs * 8, sA + c * 8);
            gload_lds16(Bt + (size_t)(n0 + row) * H_SZ + k0 + subs * 8, sB + c * 8);
        }
        __syncthreads();
#pragma unroll
        for (int ks = 0; ks < 2; ++ks) {
            half8 af[4], bf[4];
#pragma unroll
            for (int i = 0; i < 4; ++i) {
                int row = wr * 64 + i * 16 + l16;
                int s = (ks * 4 + quad) ^ (row & 7);   // swizzle on READ
                af[i] = *(const half8*)(sA + row * 64 + s * 8);
            }
#pragma unroll
            for (int j = 0; j < 4; ++j) {
                int row = wc * 64 + j * 16 + l16;
                int s = (ks * 4 + quad) ^ (row & 7);
                bf[j] = *(const half8*)(sB + row * 64 + s * 8);
            }
#pragma unroll
            for (int i = 0; i < 4; ++i)
#pragma unroll
                for (int j = 0; j < 4; ++j)
                    acc[i][j] = mfma16(af[i], bf[j], acc[i][j]);
        }
        __syncthreads();
    }
#pragma unroll
    for (int j = 0; j < 4; ++j) {
        int colg = n0 + wc * 64 + j * 16 + l16;
        if (colg >= V_SZ) continue;
        float bb = bias[colg];
#pragma unroll
        for (int i = 0; i < 4; ++i) {
#pragma unroll
            for (int r = 0; r < 4; ++r) {
                int rowg = m0 + wr * 64 + i * 16 + quad * 4 + r;
                C[(size_t)rowg * V_SZ + colg] = acc[i][j][r] + bb;
            }
        }
    }
}

// ---------------- persistent recurrence kernel: canary dataflow ----------------
// Grid: 128 wgs = layer(2) x batch-group(8, 16 rows) x H-slice(8, 64 cols).
// No flags, no tid0 serialization: hs slots 1..S are pre-poisoned with fp16
// canary; consumers cooperatively stage the needed 16x512 h-tile(s) into
// double-buffered LDS with device-coherent 16B loads, retrying until no
// element is canary. One __syncthreads per step (staging -> frag reads).
// Producers publish h via plain 8B agent-scope relaxed stores.
__global__ __launch_bounds__(256, 1) void rnn_persistent(
    const int* __restrict__ tok, const float* __restrict__ emb2,
    const _Float16* __restrict__ wih16, const _Float16* __restrict__ whh16,
    const float* __restrict__ b_hh,
    _Float16* __restrict__ hs0, _Float16* __restrict__ hs1,
    float* __restrict__ hfinal)
{
    const int wg = blockIdx.x;
    const int layer = wg >> 6;
    const int bg = (wg >> 3) & 7;
    const int hw = wg & 7;
    const int tid = threadIdx.x;
    const int lane = tid & 63;
    const int wave = tid >> 6;
    const int quad = lane >> 4, l16 = lane & 15;
    const int b0 = bg * 16;
    const int wcol = hw * 64 + wave * 16 + l16;       // weight row this lane loads (A-frag)
    const int ocol = hw * 64 + wave * 16 + quad * 4;  // lane's 4 output columns
    const int brow = b0 + l16;                        // lane's batch row

    // LDS staging: [2 bufs][16 rows][520 halves] per tile. Stride 520 halves
    // (=1040B, 260 dw % 32 = 4) gives the LDSS-style 2-way-free b128 pattern.
    __shared__ __align__(16) _Float16 sH0[2][16 * 520];  // L0: h_self(t) / L1: h0(t+1)
    __shared__ __align__(16) _Float16 sH1[2][16 * 520];  // L1 only: h1(t)

    // Preload weight A-fragments (plain cached loads; weights are static).
    half8 bf_hh[16];
    const _Float16* whh = whh16 + (size_t)layer * H_SZ * H_SZ + (size_t)wcol * H_SZ;
#pragma unroll
    for (int kk = 0; kk < 16; ++kk)
        bf_hh[kk] = *(const half8*)(whh + kk * 32 + quad * 8);
    half8 bf_ih[16];
    if (layer == 1) {
        const _Float16* wih = wih16 + (size_t)H_SZ * H_SZ + (size_t)wcol * H_SZ;
#pragma unroll
        for (int kk = 0; kk < 16; ++kk)
            bf_ih[kk] = *(const half8*)(wih + kk * 32 + quad * 8);
    }
    floatx4 bias1 = (floatx4){0.f, 0.f, 0.f, 0.f};
    if (layer == 1) bias1 = *(const floatx4*)(b_hh + H_SZ + ocol);

    // Staging assignment: thread tid owns 16B slot (tid&63) of rows
    // (tid>>6)+{0,4,8,12}. Per ds_write, a wave covers one full 1KB row
    // (fully-coalesced 16-line global reads; 2-way-free LDS writes).
    const int slot = tid & 63;
    const int r0 = tid >> 6;
    const size_t rowstep = 4 * (size_t)H_SZ;

    for (int t = 0; t < S_LEN; ++t) {
        const int buf = t & 1;
        _Float16* d0 = &sH0[buf][r0 * 520 + slot * 8];
        _Float16* d1 = &sH1[buf][r0 * 520 + slot * 8];

        if (layer == 0) {
            const _Float16* s0 = hs0 + ((size_t)t * B_SZ + b0 + r0) * H_SZ + slot * 8;
            u32x4 v0, v1, v2, v3; bool bad;
            do {
                v0 = ld16_sc(s0);
                v1 = ld16_sc(s0 + rowstep);
                v2 = ld16_sc(s0 + 2 * rowstep);
                v3 = ld16_sc(s0 + 3 * rowstep);
                asm volatile("s_waitcnt vmcnt(0)" ::: "memory");
                __builtin_amdgcn_sched_barrier(0);
                bad = has_canary(v0) || has_canary(v1) || has_canary(v2) || has_canary(v3);
            } while (__builtin_expect(bad, 0));
            *(u32x4*)(d0)            = v0;
            *(u32x4*)(d0 + 4 * 520)  = v1;
            *(u32x4*)(d0 + 8 * 520)  = v2;
            *(u32x4*)(d0 + 12 * 520) = v3;
        } else {
            const _Float16* s0 = hs0 + ((size_t)(t + 1) * B_SZ + b0 + r0) * H_SZ + slot * 8;
            const _Float16* s1 = hs1 + ((size_t)t * B_SZ + b0 + r0) * H_SZ + slot * 8;
            u32x4 v0, v1, v2, v3, w0, w1, w2, w3; bool bad;
            do {
                v0 = ld16_sc(s0);
                v1 = ld16_sc(s0 + rowstep);
                v2 = ld16_sc(s0 + 2 * rowstep);
                v3 = ld16_sc(s0 + 3 * rowstep);
                w0 = ld16_sc(s1);
                w1 = ld16_sc(s1 + rowstep);
                w2 = ld16_sc(s1 + 2 * rowstep);
                w3 = ld16_sc(s1 + 3 * rowstep);
                asm volatile("s_waitcnt vmcnt(0)" ::: "memory");
                __builtin_amdgcn_sched_barrier(0);
                bad = has_canary(v0) || has_canary(v1) || has_canary(v2) || has_canary(v3)
                   || has_canary(w0) || has_canary(w1) || has_canary(w2) || has_canary(w3);
            } while (__builtin_expect(bad, 0));
            *(u32x4*)(d0)            = v0;
            *(u32x4*)(d0 + 4 * 520)  = v1;
            *(u32x4*)(d0 + 8 * 520)  = v2;
            *(u32x4*)(d0 + 12 * 520) = v3;
            *(u32x4*)(d1)            = w0;
            *(u32x4*)(d1 + 4 * 520)  = w1;
            *(u32x4*)(d1 + 8 * 520)  = w2;
            *(u32x4*)(d1 + 12 * 520) = w3;
        }
        __syncthreads();   // staging(t) complete; dbl-buffer removes end barrier

        floatx4 acc;
        if (layer == 0) {
            const int tk = tok[t * B_SZ + brow];
            floatx4 a0 = *(const floatx4*)(emb2 + (size_t)tk * H_SZ + ocol); // incl. b_hh[0]
            floatx4 a1 = (floatx4){0.f, 0.f, 0.f, 0.f};
            const _Float16* hb = &sH0[buf][l16 * 520 + quad * 8];
#pragma unroll
            for (int kk = 0; kk < 8; ++kk) {
                a0 = mfma16(bf_hh[kk],     *(const half8*)(hb + kk * 32), a0);
                a1 = mfma16(bf_hh[kk + 8], *(const half8*)(hb + (kk + 8) * 32), a1);
            }
            acc = a0 + a1;
        } else {
            floatx4 a0 = bias1;
            floatx4 a1 = (floatx4){0.f, 0.f, 0.f, 0.f};
            floatx4 a2 = (floatx4){0.f, 0.f, 0.f, 0.f};
            floatx4 a3 = (floatx4){0.f, 0.f, 0.f, 0.f};
            const _Float16* hb = &sH0[buf][l16 * 520 + quad * 8];
            const _Float16* hc = &sH1[buf][l16 * 520 + quad * 8];
#pragma unroll
            for (int kk = 0; kk < 8; ++kk) {
                a0 = mfma16(bf_ih[kk],     *(const half8*)(hb + kk * 32), a0);
                a1 = mfma16(bf_ih[kk + 8], *(const half8*)(hb + (kk + 8) * 32), a1);
                a2 = mfma16(bf_hh[kk],     *(const half8*)(hc + kk * 32), a2);
                a3 = mfma16(bf_hh[kk + 8], *(const half8*)(hc + (kk + 8) * 32), a3);
            }
            acc = (a0 + a1) + (a2 + a3);
        }

        float hv[4];
#pragma unroll
        for (int r = 0; r < 4; ++r) hv[r] = fast_tanh(acc[r]);
        union { _Float16 h[4]; u64 u; } pk;
#pragma unroll
        for (int r = 0; r < 4; ++r) pk.h[r] = (_Float16)hv[r];

        _Float16* hdst = (layer ? hs1 : hs0)
                       + ((size_t)(t + 1) * B_SZ + brow) * H_SZ + ocol;
        __hip_atomic_store((u64*)hdst, pk.u, __ATOMIC_RELAXED, __HIP_MEMORY_SCOPE_AGENT);
        if (t == S_LEN - 1) {
            floatx4 f = (floatx4){hv[0], hv[1], hv[2], hv[3]};
            *(floatx4*)(hfinal + ((size_t)layer * B_SZ + brow) * H_SZ + ocol) = f;
        }
        // no end-of-step barrier: consumers poll the data itself
    }
}

// ---------------- launch ----------------
extern "C" void kernel_launch(void* const* d_in, const int* in_sizes, int n_in,
                              void* d_out, int out_size, void* d_ws, size_t ws_size,
                              hipStream_t stream) {
    const int*   tok    = (const int*)d_in[0];
    const float* hidden = (const float*)d_in[1];
    const float* emb    = (const float*)d_in[2];
    const float* W_ih   = (const float*)d_in[3];
    const float* W_hh   = (const float*)d_in[4];
    const float* b_hh   = (const float*)d_in[5];
    const float* W_out  = (const float*)d_in[6];
    const float* b_out  = (const float*)d_in[7];
    float* out = (float*)d_out;

    char* ws = (char*)d_ws;
    size_t off = 0;
    auto alloc = [&](size_t bytes) -> void* {
        void* p = ws + off;
        off += (bytes + 255) & ~(size_t)255;
        return p;
    };
    _Float16* emb16  = (_Float16*)alloc((size_t)V_SZ * H_SZ * 2);
    _Float16* wih16  = (_Float16*)alloc((size_t)2 * H_SZ * H_SZ * 2);
    _Float16* whh16  = (_Float16*)alloc((size_t)2 * H_SZ * H_SZ * 2);
    _Float16* wout16 = (_Float16*)alloc((size_t)VP_SZ * H_SZ * 2);
    float*    emb2   = (float*)alloc((size_t)V_SZ * H_SZ * 4);
    _Float16* hs0    = (_Float16*)alloc((size_t)(S_LEN + 1) * B_SZ * H_SZ * 2);
    _Float16* hs1    = (_Float16*)alloc((size_t)(S_LEN + 1) * B_SZ * H_SZ * 2);
    // total ws use ~77 MB

    cast_f16_kernel<<<dim3((V_SZ * H_SZ + 255) / 256), dim3(256), 0, stream>>>(emb, emb16, V_SZ * H_SZ);
    cast_f16_kernel<<<dim3((2 * H_SZ * H_SZ + 255) / 256), dim3(256), 0, stream>>>(W_ih, wih16, 2 * H_SZ * H_SZ);
    cast_f16_kernel<<<dim3((2 * H_SZ * H_SZ + 255) / 256), dim3(256), 0, stream>>>(W_hh, whh16, 2 * H_SZ * H_SZ);
    cast_f16_kernel<<<dim3((B_SZ * H_SZ + 255) / 256), dim3(256), 0, stream>>>(hidden, hs0, B_SZ * H_SZ);
    cast_f16_kernel<<<dim3((B_SZ * H_SZ + 255) / 256), dim3(256), 0, stream>>>(hidden + (size_t)B_SZ * H_SZ, hs1, B_SZ * H_SZ);
    build_wout_kernel<<<dim3((VP_SZ * H_SZ + 255) / 256), dim3(256), 0, stream>>>(W_out, wout16);
    poison_kernel<<<dim3(8192), dim3(256), 0, stream>>>(hs0, hs1);

    // emb2[v,:] = emb[v,:] @ W_ih[0].T + b_hh[0]  (M=10000, N=512, K=512)
    gemm_f16_kernel<<<dim3(79, 4), dim3(256), 0, stream>>>(
        emb16, H_SZ, V_SZ, wih16, H_SZ, emb2, (long)H_SZ, H_SZ, b_hh, H_SZ);

    // full recurrence (both layers, dataflow-pipelined)
    rnn_persistent<<<dim3(128), dim3(256), 0, stream>>>(
        tok, emb2, wih16, whh16, b_hh, hs0, hs1,
        out + (size_t)S_LEN * B_SZ * V_SZ);

    // logits[t*B+b, :] = h1[t,b,:] @ W_out.T + b_out  (M=16384, N=10240->10000, K=512)
    gemm_lds_kernel<<<dim3(128, 80), dim3(256), 0, stream>>>(
        hs1 + (size_t)B_SZ * H_SZ, wout16, out, b_out);
}